// Round 2
// baseline (496.327 us; speedup 1.0000x reference)
//
#include <hip/hip_runtime.h>
#include <hip/hip_bf16.h>
#include <stdint.h>

#define Bdim 64
#define Sdim 512
#define Hdim 768
#define G3   2304

typedef float f32x4 __attribute__((ext_vector_type(4)));
typedef short s16x8 __attribute__((ext_vector_type(8)));
typedef short s16x4 __attribute__((ext_vector_type(4)));

__device__ __forceinline__ float bf2f(unsigned short u){
  union { unsigned int i; float f; } c; c.i = ((unsigned int)u) << 16; return c.f;
}
__device__ __forceinline__ unsigned short f2bf(float f){
  union { float f; unsigned int i; } c; c.f = f;
  unsigned int x = c.i;
  return (unsigned short)((x + 0x7fffu + ((x >> 16) & 1u)) >> 16);
}
__device__ __forceinline__ float fast_tanh(float x){
  float e = __expf(2.f * x);
  return 1.f - 2.f / (e + 1.f);
}
__device__ __forceinline__ float fast_sigmoid(float x){
  return 1.f / (1.f + __expf(-x));
}

// ---------------- conversions / transposes ----------------

__global__ __launch_bounds__(256) void k_conv_bf16(const float* __restrict__ src,
                                                   unsigned short* __restrict__ dst, int n8){
  int i = blockIdx.x * 256 + threadIdx.x;
  if (i >= n8) return;
  const float4* s = (const float4*)src;
  float4 a = s[2*i], b = s[2*i+1];
  uint4 o;
  o.x = (unsigned)f2bf(a.x) | ((unsigned)f2bf(a.y) << 16);
  o.y = (unsigned)f2bf(a.z) | ((unsigned)f2bf(a.w) << 16);
  o.z = (unsigned)f2bf(b.x) | ((unsigned)f2bf(b.y) << 16);
  o.w = (unsigned)f2bf(b.z) | ((unsigned)f2bf(b.w) << 16);
  ((uint4*)dst)[i] = o;
}

// 4 tensors f32 -> bf16 in one dispatch (cumulative n8 counts)
__global__ __launch_bounds__(256) void k_conv4(const float* __restrict__ s0, unsigned short* __restrict__ d0, int c0,
                                               const float* __restrict__ s1, unsigned short* __restrict__ d1, int c1,
                                               const float* __restrict__ s2, unsigned short* __restrict__ d2, int c2,
                                               const float* __restrict__ s3, unsigned short* __restrict__ d3, int c3){
  int i = blockIdx.x * 256 + threadIdx.x;
  const float* s; unsigned short* d; int j;
  if (i < c0) { s = s0; d = d0; j = i; }
  else if (i < c0 + c1) { s = s1; d = d1; j = i - c0; }
  else if (i < c0 + c1 + c2) { s = s2; d = d2; j = i - c0 - c1; }
  else if (i < c0 + c1 + c2 + c3) { s = s3; d = d3; j = i - c0 - c1 - c2; }
  else return;
  const float4* sp = (const float4*)s;
  float4 a = sp[2*j], b = sp[2*j+1];
  uint4 o;
  o.x = (unsigned)f2bf(a.x) | ((unsigned)f2bf(a.y) << 16);
  o.y = (unsigned)f2bf(a.z) | ((unsigned)f2bf(a.w) << 16);
  o.z = (unsigned)f2bf(b.x) | ((unsigned)f2bf(b.y) << 16);
  o.w = (unsigned)f2bf(b.z) | ((unsigned)f2bf(b.w) << 16);
  ((uint4*)d)[j] = o;
}

// src[768][768] f32 -> dst[n][k] bf16 (transposed)
__global__ __launch_bounds__(256) void k_transpose_ws(const float* __restrict__ src,
                                                      unsigned short* __restrict__ dst){
  __shared__ float tile[32][33];
  int bx = blockIdx.x * 32, by = blockIdx.y * 32;
  int tx = threadIdx.x % 32, ty = threadIdx.x / 32;
  for (int j = ty; j < 32; j += 8) tile[j][tx] = src[(size_t)(by + j) * Hdim + bx + tx];
  __syncthreads();
  for (int j = ty; j < 32; j += 8) dst[(size_t)(bx + j) * Hdim + by + tx] = f2bf(tile[tx][j]);
}

// 4 square transposes in one dispatch (z selects pair)
__global__ __launch_bounds__(256) void k_transpose4(const float* __restrict__ s0, unsigned short* __restrict__ d0,
                                                    const float* __restrict__ s1, unsigned short* __restrict__ d1,
                                                    const float* __restrict__ s2, unsigned short* __restrict__ d2,
                                                    const float* __restrict__ s3, unsigned short* __restrict__ d3){
  const float* src; unsigned short* dst;
  switch (blockIdx.z) {
    case 0: src = s0; dst = d0; break;
    case 1: src = s1; dst = d1; break;
    case 2: src = s2; dst = d2; break;
    default: src = s3; dst = d3; break;
  }
  __shared__ float tile[32][33];
  int bx = blockIdx.x * 32, by = blockIdx.y * 32;
  int tx = threadIdx.x % 32, ty = threadIdx.x / 32;
  for (int j = ty; j < 32; j += 8) tile[j][tx] = src[(size_t)(by + j) * Hdim + bx + tx];
  __syncthreads();
  for (int j = ty; j < 32; j += 8) dst[(size_t)(bx + j) * Hdim + by + tx] = f2bf(tile[tx][j]);
}

// ---------------- Se = SEb @ ws (bf16 MFMA, XCD swizzle + reg prefetch) ----------------
__global__ __launch_bounds__(256) void k_gemm_se(const unsigned short* __restrict__ A,
                                                 const unsigned short* __restrict__ Bt,
                                                 unsigned short* __restrict__ C){
  __shared__ unsigned short As[128 * 64];
  __shared__ unsigned short Bs[128 * 64];
  const int t = threadIdx.x;
  const int lane = t & 63;
  const int w = t >> 6, wr = w >> 1, wc = w & 1;
  // bijective chunked XCD swizzle: 1536 blocks, 8 XCDs, 192 per chunk
  int bid = blockIdx.x;
  int swz = (bid & 7) * 192 + (bid >> 3);
  const int m0 = (swz / 6) * 128, n0 = (swz % 6) * 128;

  f32x4 acc[4][4];
  #pragma unroll
  for (int m = 0; m < 4; m++)
    #pragma unroll
    for (int n = 0; n < 4; n++) acc[m][n] = (f32x4){0.f, 0.f, 0.f, 0.f};

  uint4 ra[4], rb[4];
  #pragma unroll
  for (int i = 0; i < 4; i++) {
    int L = t * 16 + i * 4096, row = L >> 7, off = L & 127;
    ra[i] = *(const uint4*)((const char*)A  + ((size_t)(m0 + row) * Hdim) * 2 + off);
    rb[i] = *(const uint4*)((const char*)Bt + ((size_t)(n0 + row) * Hdim) * 2 + off);
  }

  for (int k0 = 0; k0 < Hdim; k0 += 64) {
    #pragma unroll
    for (int i = 0; i < 4; i++) {
      int L = t * 16 + i * 4096, row = L >> 7, off = L & 127;
      int soff = off ^ ((row & 7) << 4);
      *(uint4*)((char*)As + row * 128 + soff) = ra[i];
      *(uint4*)((char*)Bs + row * 128 + soff) = rb[i];
    }
    __syncthreads();
    if (k0 + 64 < Hdim) {
      #pragma unroll
      for (int i = 0; i < 4; i++) {
        int L = t * 16 + i * 4096, row = L >> 7, off = L & 127;
        ra[i] = *(const uint4*)((const char*)A  + ((size_t)(m0 + row) * Hdim + k0 + 64) * 2 + off);
        rb[i] = *(const uint4*)((const char*)Bt + ((size_t)(n0 + row) * Hdim + k0 + 64) * 2 + off);
      }
    }
    #pragma unroll
    for (int kk = 0; kk < 2; kk++) {
      s16x8 af[4], bfr[4];
      #pragma unroll
      for (int m = 0; m < 4; m++) {
        int row = wr * 64 + m * 16 + (lane & 15);
        int sw = (row & 7) << 4;
        int kb = kk * 64 + (lane >> 4) * 8;
        s16x4 lo = *(const s16x4*)((const char*)As + row * 128 + (kb ^ sw));
        s16x4 hi = *(const s16x4*)((const char*)As + row * 128 + ((kb + 32) ^ sw));
        af[m] = __builtin_shufflevector(lo, hi, 0, 1, 2, 3, 4, 5, 6, 7);
      }
      #pragma unroll
      for (int n = 0; n < 4; n++) {
        int row = wc * 64 + n * 16 + (lane & 15);
        int sw = (row & 7) << 4;
        int kb = kk * 64 + (lane >> 4) * 8;
        s16x4 lo = *(const s16x4*)((const char*)Bs + row * 128 + (kb ^ sw));
        s16x4 hi = *(const s16x4*)((const char*)Bs + row * 128 + ((kb + 32) ^ sw));
        bfr[n] = __builtin_shufflevector(lo, hi, 0, 1, 2, 3, 4, 5, 6, 7);
      }
      #pragma unroll
      for (int m = 0; m < 4; m++)
        #pragma unroll
        for (int n = 0; n < 4; n++)
          acc[m][n] = __builtin_amdgcn_mfma_f32_16x16x32_bf16(af[m], bfr[n], acc[m][n], 0, 0, 0);
    }
    __syncthreads();
  }
  #pragma unroll
  for (int m = 0; m < 4; m++) {
    int rowb = m0 + wr * 64 + m * 16 + (lane >> 4) * 4;
    #pragma unroll
    for (int n = 0; n < 4; n++) {
      int col = n0 + wc * 64 + n * 16 + (lane & 15);
      #pragma unroll
      for (int r = 0; r < 4; r++)
        C[(size_t)(rowb + r) * Hdim + col] = f2bf(acc[m][n][r]);
    }
  }
}

// ---------------- small-M MFMA GEMM: C[64][N] = A[64][768] @ Bt[N][768]^T (+D) ----------------
__global__ __launch_bounds__(256) void k_gemm_smallM(const unsigned short* __restrict__ A,
                                                     const unsigned short* __restrict__ Bt,
                                                     const float* __restrict__ D,
                                                     float* __restrict__ C,
                                                     unsigned short* __restrict__ Cb,
                                                     int N){
  __shared__ unsigned short As[64 * 64];
  __shared__ unsigned short Bs[128 * 64];
  const int t = threadIdx.x, lane = t & 63, w = t >> 6;
  const int n0 = blockIdx.x * 128;
  f32x4 acc[4][2];
  #pragma unroll
  for (int m = 0; m < 4; m++)
    #pragma unroll
    for (int n = 0; n < 2; n++) acc[m][n] = (f32x4){0.f, 0.f, 0.f, 0.f};

  for (int k0 = 0; k0 < Hdim; k0 += 64) {
    #pragma unroll
    for (int i = 0; i < 2; i++) {
      int L = t * 16 + i * 4096, row = L >> 7, off = L & 127;
      *(uint4*)((char*)As + row * 128 + (off ^ ((row & 7) << 4))) =
        *(const uint4*)((const char*)A + ((size_t)row * Hdim + k0) * 2 + off);
    }
    #pragma unroll
    for (int i = 0; i < 4; i++) {
      int L = t * 16 + i * 4096, row = L >> 7, off = L & 127;
      *(uint4*)((char*)Bs + row * 128 + (off ^ ((row & 7) << 4))) =
        *(const uint4*)((const char*)Bt + ((size_t)(n0 + row) * Hdim + k0) * 2 + off);
    }
    __syncthreads();
    #pragma unroll
    for (int kk = 0; kk < 2; kk++) {
      s16x8 af[4], bfr[2];
      int kb = kk * 64 + (lane >> 4) * 8;
      #pragma unroll
      for (int m = 0; m < 4; m++) {
        int row = m * 16 + (lane & 15);
        int sw = (row & 7) << 4;
        s16x4 lo = *(const s16x4*)((const char*)As + row * 128 + (kb ^ sw));
        s16x4 hi = *(const s16x4*)((const char*)As + row * 128 + ((kb + 32) ^ sw));
        af[m] = __builtin_shufflevector(lo, hi, 0, 1, 2, 3, 4, 5, 6, 7);
      }
      #pragma unroll
      for (int n = 0; n < 2; n++) {
        int row = w * 32 + n * 16 + (lane & 15);
        int sw = (row & 7) << 4;
        s16x4 lo = *(const s16x4*)((const char*)Bs + row * 128 + (kb ^ sw));
        s16x4 hi = *(const s16x4*)((const char*)Bs + row * 128 + ((kb + 32) ^ sw));
        bfr[n] = __builtin_shufflevector(lo, hi, 0, 1, 2, 3, 4, 5, 6, 7);
      }
      #pragma unroll
      for (int m = 0; m < 4; m++)
        #pragma unroll
        for (int n = 0; n < 2; n++)
          acc[m][n] = __builtin_amdgcn_mfma_f32_16x16x32_bf16(af[m], bfr[n], acc[m][n], 0, 0, 0);
    }
    __syncthreads();
  }
  #pragma unroll
  for (int m = 0; m < 4; m++) {
    int rowb = m * 16 + (lane >> 4) * 4;
    #pragma unroll
    for (int n = 0; n < 2; n++) {
      int col = n0 + w * 32 + n * 16 + (lane & 15);
      #pragma unroll
      for (int r = 0; r < 4; r++) {
        float v = acc[m][n][r];
        if (D) v += D[(size_t)(rowb + r) * N + col];
        C[(size_t)(rowb + r) * N + col] = v;
        if (Cb) Cb[(size_t)(rowb + r) * N + col] = f2bf(v);
      }
    }
  }
}

// ---------------- scores[b,s] = sum_k tanh(Se[b,s,k] + V[b,k]) * w[k] ----------------
__global__ __launch_bounds__(256) void k_scores(const unsigned short* __restrict__ Seb,
                                                const float* __restrict__ V,
                                                const float* __restrict__ wv,
                                                float* __restrict__ scores){
  int b = blockIdx.y;
  int s_base = blockIdx.x * 16;
  int t = threadIdx.x, lane = t & 63, w = t >> 6;
  const float* Vb = V + (size_t)b * Hdim;
  float4 v0 = *(const float4*)(Vb + lane * 8);
  float4 v1 = *(const float4*)(Vb + lane * 8 + 4);
  float4 v2 = *(const float4*)(Vb + 512 + lane * 4);
  float4 w0 = *(const float4*)(wv + lane * 8);
  float4 w1 = *(const float4*)(wv + lane * 8 + 4);
  float4 w2 = *(const float4*)(wv + 512 + lane * 4);
  #pragma unroll
  for (int si = 0; si < 4; si++) {
    int s = s_base + w * 4 + si;
    const unsigned short* rp = Seb + ((size_t)b * Sdim + s) * Hdim;
    ushort4 p0 = *(const ushort4*)(rp + lane * 8);
    ushort4 p1 = *(const ushort4*)(rp + lane * 8 + 4);
    ushort4 p2 = *(const ushort4*)(rp + 512 + lane * 4);
    float acc;
    acc  = fast_tanh(bf2f(p0.x) + v0.x) * w0.x;
    acc += fast_tanh(bf2f(p0.y) + v0.y) * w0.y;
    acc += fast_tanh(bf2f(p0.z) + v0.z) * w0.z;
    acc += fast_tanh(bf2f(p0.w) + v0.w) * w0.w;
    acc += fast_tanh(bf2f(p1.x) + v1.x) * w1.x;
    acc += fast_tanh(bf2f(p1.y) + v1.y) * w1.y;
    acc += fast_tanh(bf2f(p1.z) + v1.z) * w1.z;
    acc += fast_tanh(bf2f(p1.w) + v1.w) * w1.w;
    acc += fast_tanh(bf2f(p2.x) + v2.x) * w2.x;
    acc += fast_tanh(bf2f(p2.y) + v2.y) * w2.y;
    acc += fast_tanh(bf2f(p2.z) + v2.z) * w2.z;
    acc += fast_tanh(bf2f(p2.w) + v2.w) * w2.w;
    #pragma unroll
    for (int o = 32; o; o >>= 1) acc += __shfl_xor(acc, o);
    if (lane == 0) scores[(size_t)b * Sdim + s] = acc;
  }
}

// ---------------- softmax then * mask / denom ----------------
__global__ __launch_bounds__(512) void k_softmax(const float* __restrict__ scores,
                                                 const float* __restrict__ mask,
                                                 float* __restrict__ mwn){
  int b = blockIdx.x, t = threadIdx.x, lane = t & 63, w = t >> 6;
  __shared__ float r1[8], r2[8];
  float x = scores[(size_t)b * Sdim + t];
  float mk = mask[(size_t)b * Sdim + t];
  float mx = x;
  #pragma unroll
  for (int o = 32; o; o >>= 1) mx = fmaxf(mx, __shfl_xor(mx, o));
  if (lane == 0) r1[w] = mx;
  __syncthreads();
  mx = r1[0];
  #pragma unroll
  for (int i = 1; i < 8; i++) mx = fmaxf(mx, r1[i]);
  __syncthreads();
  float e = __expf(x - mx);
  float se = e, sm = mk;
  #pragma unroll
  for (int o = 32; o; o >>= 1) { se += __shfl_xor(se, o); sm += __shfl_xor(sm, o); }
  if (lane == 0) { r1[w] = se; r2[w] = sm; }
  __syncthreads();
  se = 0.f; sm = 0.f;
  #pragma unroll
  for (int i = 0; i < 8; i++) { se += r1[i]; sm += r2[i]; }
  mwn[(size_t)b * Sdim + t] = (e / se) * mk / sm;
}

// ---------------- at partial (bf16 input) ----------------
__global__ __launch_bounds__(192) void k_at_part_bf16(const unsigned short* __restrict__ SEb,
                                                      const float* __restrict__ mwn,
                                                      float* __restrict__ at_part){
  int sc = blockIdx.x, b = blockIdx.y;
  int t = threadIdx.x;
  __shared__ float msh[64];
  __shared__ float half0[96 * 8];
  if (t < 64) msh[t] = mwn[(size_t)b * Sdim + sc * 64 + t];
  __syncthreads();
  int hseg = t % 96, sh = t / 96;
  const unsigned short* base = SEb + ((size_t)b * Sdim + sc * 64 + sh * 32) * Hdim + hseg * 8;
  float acc[8] = {0, 0, 0, 0, 0, 0, 0, 0};
  for (int s = 0; s < 32; s++) {
    float m = msh[sh * 32 + s];
    ushort4 a = *(const ushort4*)(base + (size_t)s * Hdim);
    ushort4 c = *(const ushort4*)(base + (size_t)s * Hdim + 4);
    acc[0] += m * bf2f(a.x); acc[1] += m * bf2f(a.y); acc[2] += m * bf2f(a.z); acc[3] += m * bf2f(a.w);
    acc[4] += m * bf2f(c.x); acc[5] += m * bf2f(c.y); acc[6] += m * bf2f(c.z); acc[7] += m * bf2f(c.w);
  }
  if (sh == 0) {
    #pragma unroll
    for (int j = 0; j < 8; j++) half0[hseg * 8 + j] = acc[j];
  }
  __syncthreads();
  if (sh == 1) {
    float* op = at_part + ((size_t)sc * Bdim + b) * Hdim + hseg * 8;
    #pragma unroll
    for (int j = 0; j < 8; j++) op[j] = acc[j] + half0[hseg * 8 + j];
  }
}

// ---------------- at partial (f32 input, fallback when ws too small) ----------------
__global__ __launch_bounds__(192) void k_at_part_f32(const float* __restrict__ SE,
                                                     const float* __restrict__ mwn,
                                                     float* __restrict__ at_part){
  int sc = blockIdx.x, b = blockIdx.y;
  int t = threadIdx.x;
  __shared__ float msh[64];
  __shared__ float half0[96 * 8];
  if (t < 64) msh[t] = mwn[(size_t)b * Sdim + sc * 64 + t];
  __syncthreads();
  int hseg = t % 96, sh = t / 96;
  const float* base = SE + ((size_t)b * Sdim + sc * 64 + sh * 32) * Hdim + hseg * 8;
  float acc[8] = {0, 0, 0, 0, 0, 0, 0, 0};
  for (int s = 0; s < 32; s++) {
    float m = msh[sh * 32 + s];
    float4 a = *(const float4*)(base + (size_t)s * Hdim);
    float4 c = *(const float4*)(base + (size_t)s * Hdim + 4);
    acc[0] += m * a.x; acc[1] += m * a.y; acc[2] += m * a.z; acc[3] += m * a.w;
    acc[4] += m * c.x; acc[5] += m * c.y; acc[6] += m * c.z; acc[7] += m * c.w;
  }
  if (sh == 0) {
    #pragma unroll
    for (int j = 0; j < 8; j++) half0[hseg * 8 + j] = acc[j];
  }
  __syncthreads();
  if (sh == 1) {
    float* op = at_part + ((size_t)sc * Bdim + b) * Hdim + hseg * 8;
    #pragma unroll
    for (int j = 0; j < 8; j++) op[j] = acc[j] + half0[hseg * 8 + j];
  }
}

// ---------------- at reduce: sum 8 partials -> bf16 ----------------
__global__ __launch_bounds__(256) void k_at_reduce(const float* __restrict__ at_part,
                                                   unsigned short* __restrict__ atb){
  int i = blockIdx.x * 256 + threadIdx.x;  // 64*768
  float s = 0.f;
  #pragma unroll
  for (int p = 0; p < 8; p++) s += at_part[(size_t)p * (Bdim * Hdim) + i];
  atb[i] = f2bf(s);
}

// ---------------- GRU elementwise ----------------
__global__ __launch_bounds__(256) void k_gru_elem2(const float* __restrict__ gi,
                                                   const float* __restrict__ gh,
                                                   const float* __restrict__ h,
                                                   float* __restrict__ hout,
                                                   unsigned short* __restrict__ hbout){
  int i = blockIdx.x * 256 + threadIdx.x;  // 64*768
  int b = i / Hdim, g = i % Hdim;
  const float* gib = gi + (size_t)b * G3;
  const float* ghb = gh + (size_t)b * G3;
  float r = fast_sigmoid(gib[g] + ghb[g]);
  float z = fast_sigmoid(gib[Hdim + g] + ghb[Hdim + g]);
  float n = fast_tanh(gib[2 * Hdim + g] + r * ghb[2 * Hdim + g]);
  float ho = (1.f - z) * n + z * h[i];
  hout[i] = ho;
  hbout[i] = f2bf(ho);
}

// ---------------- host ----------------
extern "C" void kernel_launch(void* const* d_in, const int* in_sizes, int n_in,
                              void* d_out, int out_size, void* d_ws, size_t ws_size,
                              hipStream_t stream) {
  const float* sr   = (const float*)d_in[0];
  const float* mask = (const float*)d_in[1];
  const float* asp  = (const float*)d_in[2];
  const float* SE   = (const float*)d_in[3];
  const float* ws_  = (const float*)d_in[4];
  const float* wa   = (const float*)d_in[5];
  const float* wv   = (const float*)d_in[6];
  const float* whs  = (const float*)d_in[7];
  const float* wd1  = (const float*)d_in[8];
  const float* wd   = (const float*)d_in[9];
  const float* w_ih = (const float*)d_in[10];
  const float* w_hh = (const float*)d_in[11];
  float* out = (float*)d_out;

  char* p = (char*)d_ws;
  size_t offA = 0;
  auto A_ = [&](size_t b) -> char* { char* r = p + offA; offA += b; return r; };
  unsigned short* Seb  = (unsigned short*)A_(50331648);  // Se bf16, alive all layers
  unsigned short* wsbT = (unsigned short*)A_(1179648);   // ws^T bf16 (needed pre-GEMM)
  unsigned short* SEb  = (unsigned short*)A_(50331648);  // SE bf16 (GEMM A; pool if it fits)

  const size_t othersBytes = 16089088;
  bool keepSEb = (offA + othersBytes) <= ws_size;
  char* q = keepSEb ? (p + offA) : (char*)SEb;  // fallback: alias over SEb (dead after GEMM)
  size_t o2 = 0;
  auto B_ = [&](size_t b) -> char* { char* r = q + o2; o2 += b; return r; };
  unsigned short* w_ihb = (unsigned short*)B_(3538944);
  unsigned short* w_hhb = (unsigned short*)B_(3538944);
  unsigned short* wd1T  = (unsigned short*)B_(1179648);
  unsigned short* wdT   = (unsigned short*)B_(1179648);
  unsigned short* waT   = (unsigned short*)B_(1179648);
  unsigned short* whsT  = (unsigned short*)B_(1179648);
  unsigned short* srb   = (unsigned short*)B_(98304);
  unsigned short* aspb  = (unsigned short*)B_(98304);
  float* Aasp    = (float*)B_(196608);
  float* V       = (float*)B_(196608);
  float* scores  = (float*)B_(131072);
  float* mwn     = (float*)B_(131072);
  float* at_part = (float*)B_(1572864);
  unsigned short* atb = (unsigned short*)B_(98304);
  float* gi      = (float*)B_(589824);
  float* gh      = (float*)B_(589824);
  float* hA      = (float*)B_(196608);
  float* hB      = (float*)B_(196608);
  unsigned short* hbA = (unsigned short*)B_(98304);
  unsigned short* hbB = (unsigned short*)B_(98304);
  if (!keepSEb && (102 * 1024 * 1024ull > ws_size)) return;  // need >= ~102MB

  // ---- prep ----
  k_conv_bf16<<<dim3(12288), dim3(256), 0, stream>>>(SE, SEb, 3145728);
  k_transpose_ws<<<dim3(24, 24), dim3(256), 0, stream>>>(ws_, wsbT);
  k_gemm_se<<<dim3(1536), dim3(256), 0, stream>>>(SEb, wsbT, Seb);
  // after GEMM, SEb region reusable in fallback layout
  k_transpose4<<<dim3(24, 24, 4), dim3(256), 0, stream>>>(wd1, wd1T, wd, wdT, wa, waT, whs, whsT);
  k_conv4<<<dim3(1776), dim3(256), 0, stream>>>(w_ih, w_ihb, 221184, w_hh, w_hhb, 221184,
                                                sr, srb, 6144, asp, aspb, 6144);
  k_gemm_smallM<<<dim3(6), dim3(256), 0, stream>>>(aspb, waT, nullptr, Aasp, nullptr, Hdim);
  k_gemm_smallM<<<dim3(6), dim3(256), 0, stream>>>(srb, whsT, nullptr, hA, hbA, Hdim);

  // ---- layers ----
  const unsigned short* attA = srb;   // bf16 of attention h
  const float* hcur = hA;             // f32 GRU h
  const unsigned short* hbcur = hbA;  // bf16 GRU h
  for (int tl = 0; tl < 3; ++tl) {
    const unsigned short* WdT = (tl == 0) ? wd1T : wdT;
    k_gemm_smallM<<<dim3(6), dim3(256), 0, stream>>>(attA, WdT, Aasp, V, nullptr, Hdim);
    k_scores<<<dim3(32, 64), dim3(256), 0, stream>>>(Seb, V, wv, scores);
    k_softmax<<<dim3(64), dim3(512), 0, stream>>>(scores, mask, mwn);
    if (keepSEb)
      k_at_part_bf16<<<dim3(8, 64), dim3(192), 0, stream>>>(SEb, mwn, at_part);
    else
      k_at_part_f32<<<dim3(8, 64), dim3(192), 0, stream>>>(SE, mwn, at_part);
    k_at_reduce<<<dim3(192), dim3(256), 0, stream>>>(at_part, atb);
    k_gemm_smallM<<<dim3(18), dim3(256), 0, stream>>>(atb, w_ihb, nullptr, gi, nullptr, G3);
    k_gemm_smallM<<<dim3(18), dim3(256), 0, stream>>>(hbcur, w_hhb, nullptr, gh, nullptr, G3);
    float* hout = (tl == 2) ? out : ((hcur == hA) ? hB : hA);
    unsigned short* hbout = (tl == 2) ? hbB : ((hbcur == hbA) ? hbB : hbA);
    k_gru_elem2<<<dim3(192), dim3(256), 0, stream>>>(gi, gh, hcur, hout, hbout);
    hcur = hout;
    hbcur = hbout;
    attA = hbout;
  }
}

// Round 3
// 384.056 us; speedup vs baseline: 1.2923x; 1.2923x over previous
//
#include <hip/hip_runtime.h>
#include <hip/hip_bf16.h>
#include <stdint.h>

#define Bdim 64
#define Sdim 512
#define Hdim 768
#define G3   2304

typedef float f32x4 __attribute__((ext_vector_type(4)));
typedef short s16x8 __attribute__((ext_vector_type(8)));
typedef short s16x4 __attribute__((ext_vector_type(4)));

__device__ __forceinline__ float bf2f(unsigned short u){
  union { unsigned int i; float f; } c; c.i = ((unsigned int)u) << 16; return c.f;
}
__device__ __forceinline__ unsigned short f2bf(float f){
  union { float f; unsigned int i; } c; c.f = f;
  unsigned int x = c.i;
  return (unsigned short)((x + 0x7fffu + ((x >> 16) & 1u)) >> 16);
}
__device__ __forceinline__ float fast_tanh(float x){
  float e = __expf(2.f * x);
  return 1.f - 2.f / (e + 1.f);
}
__device__ __forceinline__ float fast_sigmoid(float x){
  return 1.f / (1.f + __expf(-x));
}

// ---------------- conversions / transposes ----------------

__global__ __launch_bounds__(256) void k_conv_bf16(const float* __restrict__ src,
                                                   unsigned short* __restrict__ dst, int n8){
  int i = blockIdx.x * 256 + threadIdx.x;
  if (i >= n8) return;
  const float4* s = (const float4*)src;
  float4 a = s[2*i], b = s[2*i+1];
  uint4 o;
  o.x = (unsigned)f2bf(a.x) | ((unsigned)f2bf(a.y) << 16);
  o.y = (unsigned)f2bf(a.z) | ((unsigned)f2bf(a.w) << 16);
  o.z = (unsigned)f2bf(b.x) | ((unsigned)f2bf(b.y) << 16);
  o.w = (unsigned)f2bf(b.z) | ((unsigned)f2bf(b.w) << 16);
  ((uint4*)dst)[i] = o;
}

// 4 tensors f32 -> bf16 in one dispatch (cumulative n8 counts)
__global__ __launch_bounds__(256) void k_conv4(const float* __restrict__ s0, unsigned short* __restrict__ d0, int c0,
                                               const float* __restrict__ s1, unsigned short* __restrict__ d1, int c1,
                                               const float* __restrict__ s2, unsigned short* __restrict__ d2, int c2,
                                               const float* __restrict__ s3, unsigned short* __restrict__ d3, int c3){
  int i = blockIdx.x * 256 + threadIdx.x;
  const float* s; unsigned short* d; int j;
  if (i < c0) { s = s0; d = d0; j = i; }
  else if (i < c0 + c1) { s = s1; d = d1; j = i - c0; }
  else if (i < c0 + c1 + c2) { s = s2; d = d2; j = i - c0 - c1; }
  else if (i < c0 + c1 + c2 + c3) { s = s3; d = d3; j = i - c0 - c1 - c2; }
  else return;
  const float4* sp = (const float4*)s;
  float4 a = sp[2*j], b = sp[2*j+1];
  uint4 o;
  o.x = (unsigned)f2bf(a.x) | ((unsigned)f2bf(a.y) << 16);
  o.y = (unsigned)f2bf(a.z) | ((unsigned)f2bf(a.w) << 16);
  o.z = (unsigned)f2bf(b.x) | ((unsigned)f2bf(b.y) << 16);
  o.w = (unsigned)f2bf(b.z) | ((unsigned)f2bf(b.w) << 16);
  ((uint4*)d)[j] = o;
}

// src[768][768] f32 -> dst[n][k] bf16 (transposed)
__global__ __launch_bounds__(256) void k_transpose_ws(const float* __restrict__ src,
                                                      unsigned short* __restrict__ dst){
  __shared__ float tile[32][33];
  int bx = blockIdx.x * 32, by = blockIdx.y * 32;
  int tx = threadIdx.x % 32, ty = threadIdx.x / 32;
  for (int j = ty; j < 32; j += 8) tile[j][tx] = src[(size_t)(by + j) * Hdim + bx + tx];
  __syncthreads();
  for (int j = ty; j < 32; j += 8) dst[(size_t)(bx + j) * Hdim + by + tx] = f2bf(tile[tx][j]);
}

// 4 square transposes in one dispatch (z selects pair)
__global__ __launch_bounds__(256) void k_transpose4(const float* __restrict__ s0, unsigned short* __restrict__ d0,
                                                    const float* __restrict__ s1, unsigned short* __restrict__ d1,
                                                    const float* __restrict__ s2, unsigned short* __restrict__ d2,
                                                    const float* __restrict__ s3, unsigned short* __restrict__ d3){
  const float* src; unsigned short* dst;
  switch (blockIdx.z) {
    case 0: src = s0; dst = d0; break;
    case 1: src = s1; dst = d1; break;
    case 2: src = s2; dst = d2; break;
    default: src = s3; dst = d3; break;
  }
  __shared__ float tile[32][33];
  int bx = blockIdx.x * 32, by = blockIdx.y * 32;
  int tx = threadIdx.x % 32, ty = threadIdx.x / 32;
  for (int j = ty; j < 32; j += 8) tile[j][tx] = src[(size_t)(by + j) * Hdim + bx + tx];
  __syncthreads();
  for (int j = ty; j < 32; j += 8) dst[(size_t)(bx + j) * Hdim + by + tx] = f2bf(tile[tx][j]);
}

// ---------------- Se = SEb @ ws (bf16 MFMA, bijective XCD swizzle, spill-free) ----------------
__global__ __launch_bounds__(256) void k_gemm_se(const unsigned short* __restrict__ A,
                                                 const unsigned short* __restrict__ Bt,
                                                 unsigned short* __restrict__ C){
  __shared__ unsigned short As[128 * 64];
  __shared__ unsigned short Bs[128 * 64];
  const int t = threadIdx.x;
  const int lane = t & 63;
  const int w = t >> 6, wr = w >> 1, wc = w & 1;
  // bijective chunked XCD swizzle: 1536 blocks, 8 XCDs, 192 per chunk
  int bid = blockIdx.x;
  int swz = (bid & 7) * 192 + (bid >> 3);
  const int m0 = (swz / 6) * 128, n0 = (swz % 6) * 128;

  f32x4 acc[4][4];
  #pragma unroll
  for (int m = 0; m < 4; m++)
    #pragma unroll
    for (int n = 0; n < 4; n++) acc[m][n] = (f32x4){0.f, 0.f, 0.f, 0.f};

  for (int k0 = 0; k0 < Hdim; k0 += 64) {
    // stage 128x64 bf16 tiles, XOR-swizzled LDS (byte ^= (row&7)<<4)
    #pragma unroll
    for (int i = 0; i < 4; i++) {
      int L = t * 16 + i * 4096;
      int row = L >> 7;
      int off = L & 127;
      int soff = off ^ ((row & 7) << 4);
      uint4 va = *(const uint4*)((const char*)A  + ((size_t)(m0 + row) * Hdim + k0) * 2 + off);
      uint4 vb = *(const uint4*)((const char*)Bt + ((size_t)(n0 + row) * Hdim + k0) * 2 + off);
      *(uint4*)((char*)As + row * 128 + soff) = va;
      *(uint4*)((char*)Bs + row * 128 + soff) = vb;
    }
    __syncthreads();
    #pragma unroll
    for (int kk = 0; kk < 2; kk++) {
      s16x8 af[4], bfr[4];
      #pragma unroll
      for (int m = 0; m < 4; m++) {
        int row = wr * 64 + m * 16 + (lane & 15);
        int sw = (row & 7) << 4;
        int kb = kk * 64 + (lane >> 4) * 8;
        s16x4 lo = *(const s16x4*)((const char*)As + row * 128 + (kb ^ sw));
        s16x4 hi = *(const s16x4*)((const char*)As + row * 128 + ((kb + 32) ^ sw));
        af[m] = __builtin_shufflevector(lo, hi, 0, 1, 2, 3, 4, 5, 6, 7);
      }
      #pragma unroll
      for (int n = 0; n < 4; n++) {
        int row = wc * 64 + n * 16 + (lane & 15);
        int sw = (row & 7) << 4;
        int kb = kk * 64 + (lane >> 4) * 8;
        s16x4 lo = *(const s16x4*)((const char*)Bs + row * 128 + (kb ^ sw));
        s16x4 hi = *(const s16x4*)((const char*)Bs + row * 128 + ((kb + 32) ^ sw));
        bfr[n] = __builtin_shufflevector(lo, hi, 0, 1, 2, 3, 4, 5, 6, 7);
      }
      #pragma unroll
      for (int m = 0; m < 4; m++)
        #pragma unroll
        for (int n = 0; n < 4; n++)
          acc[m][n] = __builtin_amdgcn_mfma_f32_16x16x32_bf16(af[m], bfr[n], acc[m][n], 0, 0, 0);
    }
    __syncthreads();
  }
  #pragma unroll
  for (int m = 0; m < 4; m++) {
    int rowb = m0 + wr * 64 + m * 16 + (lane >> 4) * 4;
    #pragma unroll
    for (int n = 0; n < 4; n++) {
      int col = n0 + wc * 64 + n * 16 + (lane & 15);
      #pragma unroll
      for (int r = 0; r < 4; r++)
        C[(size_t)(rowb + r) * Hdim + col] = f2bf(acc[m][n][r]);
    }
  }
}

// ---------------- small-M MFMA GEMM: C[64][N] = A[64][768] @ Bt[N][768]^T (+D) ----------------
__global__ __launch_bounds__(256) void k_gemm_smallM(const unsigned short* __restrict__ A,
                                                     const unsigned short* __restrict__ Bt,
                                                     const float* __restrict__ D,
                                                     float* __restrict__ C,
                                                     unsigned short* __restrict__ Cb,
                                                     int N){
  __shared__ unsigned short As[64 * 64];
  __shared__ unsigned short Bs[128 * 64];
  const int t = threadIdx.x, lane = t & 63, w = t >> 6;
  const int n0 = blockIdx.x * 128;
  f32x4 acc[4][2];
  #pragma unroll
  for (int m = 0; m < 4; m++)
    #pragma unroll
    for (int n = 0; n < 2; n++) acc[m][n] = (f32x4){0.f, 0.f, 0.f, 0.f};

  for (int k0 = 0; k0 < Hdim; k0 += 64) {
    #pragma unroll
    for (int i = 0; i < 2; i++) {
      int L = t * 16 + i * 4096, row = L >> 7, off = L & 127;
      *(uint4*)((char*)As + row * 128 + (off ^ ((row & 7) << 4))) =
        *(const uint4*)((const char*)A + ((size_t)row * Hdim + k0) * 2 + off);
    }
    #pragma unroll
    for (int i = 0; i < 4; i++) {
      int L = t * 16 + i * 4096, row = L >> 7, off = L & 127;
      *(uint4*)((char*)Bs + row * 128 + (off ^ ((row & 7) << 4))) =
        *(const uint4*)((const char*)Bt + ((size_t)(n0 + row) * Hdim + k0) * 2 + off);
    }
    __syncthreads();
    #pragma unroll
    for (int kk = 0; kk < 2; kk++) {
      s16x8 af[4], bfr[2];
      int kb = kk * 64 + (lane >> 4) * 8;
      #pragma unroll
      for (int m = 0; m < 4; m++) {
        int row = m * 16 + (lane & 15);
        int sw = (row & 7) << 4;
        s16x4 lo = *(const s16x4*)((const char*)As + row * 128 + (kb ^ sw));
        s16x4 hi = *(const s16x4*)((const char*)As + row * 128 + ((kb + 32) ^ sw));
        af[m] = __builtin_shufflevector(lo, hi, 0, 1, 2, 3, 4, 5, 6, 7);
      }
      #pragma unroll
      for (int n = 0; n < 2; n++) {
        int row = w * 32 + n * 16 + (lane & 15);
        int sw = (row & 7) << 4;
        s16x4 lo = *(const s16x4*)((const char*)Bs + row * 128 + (kb ^ sw));
        s16x4 hi = *(const s16x4*)((const char*)Bs + row * 128 + ((kb + 32) ^ sw));
        bfr[n] = __builtin_shufflevector(lo, hi, 0, 1, 2, 3, 4, 5, 6, 7);
      }
      #pragma unroll
      for (int m = 0; m < 4; m++)
        #pragma unroll
        for (int n = 0; n < 2; n++)
          acc[m][n] = __builtin_amdgcn_mfma_f32_16x16x32_bf16(af[m], bfr[n], acc[m][n], 0, 0, 0);
    }
    __syncthreads();
  }
  #pragma unroll
  for (int m = 0; m < 4; m++) {
    int rowb = m * 16 + (lane >> 4) * 4;
    #pragma unroll
    for (int n = 0; n < 2; n++) {
      int col = n0 + w * 32 + n * 16 + (lane & 15);
      #pragma unroll
      for (int r = 0; r < 4; r++) {
        float v = acc[m][n][r];
        if (D) v += D[(size_t)(rowb + r) * N + col];
        C[(size_t)(rowb + r) * N + col] = v;
        if (Cb) Cb[(size_t)(rowb + r) * N + col] = f2bf(v);
      }
    }
  }
}

// ---------------- scores[b,s] = sum_k tanh(Se[b,s,k] + V[b,k]) * w[k] ----------------
__global__ __launch_bounds__(256) void k_scores(const unsigned short* __restrict__ Seb,
                                                const float* __restrict__ V,
                                                const float* __restrict__ wv,
                                                float* __restrict__ scores){
  int b = blockIdx.y;
  int s_base = blockIdx.x * 16;
  int t = threadIdx.x, lane = t & 63, w = t >> 6;
  const float* Vb = V + (size_t)b * Hdim;
  float4 v0 = *(const float4*)(Vb + lane * 8);
  float4 v1 = *(const float4*)(Vb + lane * 8 + 4);
  float4 v2 = *(const float4*)(Vb + 512 + lane * 4);
  float4 w0 = *(const float4*)(wv + lane * 8);
  float4 w1 = *(const float4*)(wv + lane * 8 + 4);
  float4 w2 = *(const float4*)(wv + 512 + lane * 4);
  #pragma unroll
  for (int si = 0; si < 4; si++) {
    int s = s_base + w * 4 + si;
    const unsigned short* rp = Seb + ((size_t)b * Sdim + s) * Hdim;
    ushort4 p0 = *(const ushort4*)(rp + lane * 8);
    ushort4 p1 = *(const ushort4*)(rp + lane * 8 + 4);
    ushort4 p2 = *(const ushort4*)(rp + 512 + lane * 4);
    float acc;
    acc  = fast_tanh(bf2f(p0.x) + v0.x) * w0.x;
    acc += fast_tanh(bf2f(p0.y) + v0.y) * w0.y;
    acc += fast_tanh(bf2f(p0.z) + v0.z) * w0.z;
    acc += fast_tanh(bf2f(p0.w) + v0.w) * w0.w;
    acc += fast_tanh(bf2f(p1.x) + v1.x) * w1.x;
    acc += fast_tanh(bf2f(p1.y) + v1.y) * w1.y;
    acc += fast_tanh(bf2f(p1.z) + v1.z) * w1.z;
    acc += fast_tanh(bf2f(p1.w) + v1.w) * w1.w;
    acc += fast_tanh(bf2f(p2.x) + v2.x) * w2.x;
    acc += fast_tanh(bf2f(p2.y) + v2.y) * w2.y;
    acc += fast_tanh(bf2f(p2.z) + v2.z) * w2.z;
    acc += fast_tanh(bf2f(p2.w) + v2.w) * w2.w;
    #pragma unroll
    for (int o = 32; o; o >>= 1) acc += __shfl_xor(acc, o);
    if (lane == 0) scores[(size_t)b * Sdim + s] = acc;
  }
}

// ---------------- softmax then * mask / denom ----------------
__global__ __launch_bounds__(512) void k_softmax(const float* __restrict__ scores,
                                                 const float* __restrict__ mask,
                                                 float* __restrict__ mwn){
  int b = blockIdx.x, t = threadIdx.x, lane = t & 63, w = t >> 6;
  __shared__ float r1[8], r2[8];
  float x = scores[(size_t)b * Sdim + t];
  float mk = mask[(size_t)b * Sdim + t];
  float mx = x;
  #pragma unroll
  for (int o = 32; o; o >>= 1) mx = fmaxf(mx, __shfl_xor(mx, o));
  if (lane == 0) r1[w] = mx;
  __syncthreads();
  mx = r1[0];
  #pragma unroll
  for (int i = 1; i < 8; i++) mx = fmaxf(mx, r1[i]);
  __syncthreads();
  float e = __expf(x - mx);
  float se = e, sm = mk;
  #pragma unroll
  for (int o = 32; o; o >>= 1) { se += __shfl_xor(se, o); sm += __shfl_xor(sm, o); }
  if (lane == 0) { r1[w] = se; r2[w] = sm; }
  __syncthreads();
  se = 0.f; sm = 0.f;
  #pragma unroll
  for (int i = 0; i < 8; i++) { se += r1[i]; sm += r2[i]; }
  mwn[(size_t)b * Sdim + t] = (e / se) * mk / sm;
}

// ---------------- at partial (bf16 input) ----------------
__global__ __launch_bounds__(192) void k_at_part_bf16(const unsigned short* __restrict__ SEb,
                                                      const float* __restrict__ mwn,
                                                      float* __restrict__ at_part){
  int sc = blockIdx.x, b = blockIdx.y;
  int t = threadIdx.x;
  __shared__ float msh[64];
  __shared__ float half0[96 * 8];
  if (t < 64) msh[t] = mwn[(size_t)b * Sdim + sc * 64 + t];
  __syncthreads();
  int hseg = t % 96, sh = t / 96;
  const unsigned short* base = SEb + ((size_t)b * Sdim + sc * 64 + sh * 32) * Hdim + hseg * 8;
  float acc[8] = {0, 0, 0, 0, 0, 0, 0, 0};
  for (int s = 0; s < 32; s++) {
    float m = msh[sh * 32 + s];
    ushort4 a = *(const ushort4*)(base + (size_t)s * Hdim);
    ushort4 c = *(const ushort4*)(base + (size_t)s * Hdim + 4);
    acc[0] += m * bf2f(a.x); acc[1] += m * bf2f(a.y); acc[2] += m * bf2f(a.z); acc[3] += m * bf2f(a.w);
    acc[4] += m * bf2f(c.x); acc[5] += m * bf2f(c.y); acc[6] += m * bf2f(c.z); acc[7] += m * bf2f(c.w);
  }
  if (sh == 0) {
    #pragma unroll
    for (int j = 0; j < 8; j++) half0[hseg * 8 + j] = acc[j];
  }
  __syncthreads();
  if (sh == 1) {
    float* op = at_part + ((size_t)sc * Bdim + b) * Hdim + hseg * 8;
    #pragma unroll
    for (int j = 0; j < 8; j++) op[j] = acc[j] + half0[hseg * 8 + j];
  }
}

// ---------------- at partial (f32 input, fallback when ws too small) ----------------
__global__ __launch_bounds__(192) void k_at_part_f32(const float* __restrict__ SE,
                                                     const float* __restrict__ mwn,
                                                     float* __restrict__ at_part){
  int sc = blockIdx.x, b = blockIdx.y;
  int t = threadIdx.x;
  __shared__ float msh[64];
  __shared__ float half0[96 * 8];
  if (t < 64) msh[t] = mwn[(size_t)b * Sdim + sc * 64 + t];
  __syncthreads();
  int hseg = t % 96, sh = t / 96;
  const float* base = SE + ((size_t)b * Sdim + sc * 64 + sh * 32) * Hdim + hseg * 8;
  float acc[8] = {0, 0, 0, 0, 0, 0, 0, 0};
  for (int s = 0; s < 32; s++) {
    float m = msh[sh * 32 + s];
    float4 a = *(const float4*)(base + (size_t)s * Hdim);
    float4 c = *(const float4*)(base + (size_t)s * Hdim + 4);
    acc[0] += m * a.x; acc[1] += m * a.y; acc[2] += m * a.z; acc[3] += m * a.w;
    acc[4] += m * c.x; acc[5] += m * c.y; acc[6] += m * c.z; acc[7] += m * c.w;
  }
  if (sh == 0) {
    #pragma unroll
    for (int j = 0; j < 8; j++) half0[hseg * 8 + j] = acc[j];
  }
  __syncthreads();
  if (sh == 1) {
    float* op = at_part + ((size_t)sc * Bdim + b) * Hdim + hseg * 8;
    #pragma unroll
    for (int j = 0; j < 8; j++) op[j] = acc[j] + half0[hseg * 8 + j];
  }
}

// ---------------- at reduce: sum 8 partials -> bf16 ----------------
__global__ __launch_bounds__(256) void k_at_reduce(const float* __restrict__ at_part,
                                                   unsigned short* __restrict__ atb){
  int i = blockIdx.x * 256 + threadIdx.x;  // 64*768
  float s = 0.f;
  #pragma unroll
  for (int p = 0; p < 8; p++) s += at_part[(size_t)p * (Bdim * Hdim) + i];
  atb[i] = f2bf(s);
}

// ---------------- GRU elementwise ----------------
__global__ __launch_bounds__(256) void k_gru_elem2(const float* __restrict__ gi,
                                                   const float* __restrict__ gh,
                                                   const float* __restrict__ h,
                                                   float* __restrict__ hout,
                                                   unsigned short* __restrict__ hbout){
  int i = blockIdx.x * 256 + threadIdx.x;  // 64*768
  int b = i / Hdim, g = i % Hdim;
  const float* gib = gi + (size_t)b * G3;
  const float* ghb = gh + (size_t)b * G3;
  float r = fast_sigmoid(gib[g] + ghb[g]);
  float z = fast_sigmoid(gib[Hdim + g] + ghb[Hdim + g]);
  float n = fast_tanh(gib[2 * Hdim + g] + r * ghb[2 * Hdim + g]);
  float ho = (1.f - z) * n + z * h[i];
  hout[i] = ho;
  hbout[i] = f2bf(ho);
}

// ---------------- host ----------------
extern "C" void kernel_launch(void* const* d_in, const int* in_sizes, int n_in,
                              void* d_out, int out_size, void* d_ws, size_t ws_size,
                              hipStream_t stream) {
  const float* sr   = (const float*)d_in[0];
  const float* mask = (const float*)d_in[1];
  const float* asp  = (const float*)d_in[2];
  const float* SE   = (const float*)d_in[3];
  const float* ws_  = (const float*)d_in[4];
  const float* wa   = (const float*)d_in[5];
  const float* wv   = (const float*)d_in[6];
  const float* whs  = (const float*)d_in[7];
  const float* wd1  = (const float*)d_in[8];
  const float* wd   = (const float*)d_in[9];
  const float* w_ih = (const float*)d_in[10];
  const float* w_hh = (const float*)d_in[11];
  float* out = (float*)d_out;

  char* p = (char*)d_ws;
  size_t offA = 0;
  auto A_ = [&](size_t b) -> char* { char* r = p + offA; offA += b; return r; };
  unsigned short* Seb  = (unsigned short*)A_(50331648);  // Se bf16, alive all layers
  unsigned short* wsbT = (unsigned short*)A_(1179648);   // ws^T bf16 (needed pre-GEMM)
  unsigned short* SEb  = (unsigned short*)A_(50331648);  // SE bf16 (GEMM A; pool if it fits)

  const size_t othersBytes = 16089088;
  bool keepSEb = (offA + othersBytes) <= ws_size;
  char* q = keepSEb ? (p + offA) : (char*)SEb;  // fallback: alias over SEb (dead after GEMM)
  size_t o2 = 0;
  auto B_ = [&](size_t b) -> char* { char* r = q + o2; o2 += b; return r; };
  unsigned short* w_ihb = (unsigned short*)B_(3538944);
  unsigned short* w_hhb = (unsigned short*)B_(3538944);
  unsigned short* wd1T  = (unsigned short*)B_(1179648);
  unsigned short* wdT   = (unsigned short*)B_(1179648);
  unsigned short* waT   = (unsigned short*)B_(1179648);
  unsigned short* whsT  = (unsigned short*)B_(1179648);
  unsigned short* srb   = (unsigned short*)B_(98304);
  unsigned short* aspb  = (unsigned short*)B_(98304);
  float* Aasp    = (float*)B_(196608);
  float* V       = (float*)B_(196608);
  float* scores  = (float*)B_(131072);
  float* mwn     = (float*)B_(131072);
  float* at_part = (float*)B_(1572864);
  unsigned short* atb = (unsigned short*)B_(98304);
  float* gi      = (float*)B_(589824);
  float* gh      = (float*)B_(589824);
  float* hA      = (float*)B_(196608);
  float* hB      = (float*)B_(196608);
  unsigned short* hbA = (unsigned short*)B_(98304);
  unsigned short* hbB = (unsigned short*)B_(98304);
  if (!keepSEb && (102 * 1024 * 1024ull > ws_size)) return;  // need >= ~102MB

  // ---- prep ----
  k_conv_bf16<<<dim3(12288), dim3(256), 0, stream>>>(SE, SEb, 3145728);
  k_transpose_ws<<<dim3(24, 24), dim3(256), 0, stream>>>(ws_, wsbT);
  k_gemm_se<<<dim3(1536), dim3(256), 0, stream>>>(SEb, wsbT, Seb);
  // after GEMM, SEb region reusable in fallback layout
  k_transpose4<<<dim3(24, 24, 4), dim3(256), 0, stream>>>(wd1, wd1T, wd, wdT, wa, waT, whs, whsT);
  k_conv4<<<dim3(1776), dim3(256), 0, stream>>>(w_ih, w_ihb, 221184, w_hh, w_hhb, 221184,
                                                sr, srb, 6144, asp, aspb, 6144);
  k_gemm_smallM<<<dim3(6), dim3(256), 0, stream>>>(aspb, waT, nullptr, Aasp, nullptr, Hdim);
  k_gemm_smallM<<<dim3(6), dim3(256), 0, stream>>>(srb, whsT, nullptr, hA, hbA, Hdim);

  // ---- layers ----
  const unsigned short* attA = srb;   // bf16 of attention h
  const float* hcur = hA;             // f32 GRU h
  const unsigned short* hbcur = hbA;  // bf16 GRU h
  for (int tl = 0; tl < 3; ++tl) {
    const unsigned short* WdT = (tl == 0) ? wd1T : wdT;
    k_gemm_smallM<<<dim3(6), dim3(256), 0, stream>>>(attA, WdT, Aasp, V, nullptr, Hdim);
    k_scores<<<dim3(32, 64), dim3(256), 0, stream>>>(Seb, V, wv, scores);
    k_softmax<<<dim3(64), dim3(512), 0, stream>>>(scores, mask, mwn);
    if (keepSEb)
      k_at_part_bf16<<<dim3(8, 64), dim3(192), 0, stream>>>(SEb, mwn, at_part);
    else
      k_at_part_f32<<<dim3(8, 64), dim3(192), 0, stream>>>(SE, mwn, at_part);
    k_at_reduce<<<dim3(192), dim3(256), 0, stream>>>(at_part, atb);
    k_gemm_smallM<<<dim3(18), dim3(256), 0, stream>>>(atb, w_ihb, nullptr, gi, nullptr, G3);
    k_gemm_smallM<<<dim3(18), dim3(256), 0, stream>>>(hbcur, w_hhb, nullptr, gh, nullptr, G3);
    float* hout = (tl == 2) ? out : ((hcur == hA) ? hB : hA);
    unsigned short* hbout = (tl == 2) ? hbB : ((hbcur == hbA) ? hbB : hbA);
    k_gru_elem2<<<dim3(192), dim3(256), 0, stream>>>(gi, gh, hcur, hout, hbout);
    hcur = hout;
    hbcur = hbout;
    attA = hbout;
  }
}